// Round 11
// baseline (1445.311 us; speedup 1.0000x reference)
//
#include <hip/hip_runtime.h>
#include <hip/hip_bf16.h>

typedef __bf16 bf16_t;
typedef __bf16 bf16x8 __attribute__((ext_vector_type(8)));
typedef float f32x4 __attribute__((ext_vector_type(4)));

#define DI __device__ __forceinline__

static constexpr int TOK = 131072;  // 32 batches * 64*64 tokens
static constexpr int NWIN = 2048;   // 32 * 64 windows

// window-order token t -> source image token (LN1 gather) == proj scatter dest.
DI int src_token(int t) {
  int b = t >> 12;
  int widx = (t >> 6) & 63;
  int n = t & 63;
  int wh = widx >> 3, ww = widx & 7;
  int i = n >> 3, j = n & 7;
  int y = ((wh << 3) + i + 4) & 63;
  int x2 = ((ww << 3) + j + 4) & 63;
  return (b << 12) + (y << 6) + x2;
}

DI f32x4 mfma16(bf16x8 a, bf16x8 b, f32x4 c) {
  return __builtin_amdgcn_mfma_f32_16x16x32_bf16(a, b, c, 0, 0, 0);
}

DI void gload_lds16(const bf16_t* g, bf16_t* l) {
  __builtin_amdgcn_global_load_lds(
      (__attribute__((address_space(1))) void*)const_cast<bf16_t*>(g),
      (__attribute__((address_space(3))) void*)l, 16, 0, 0);
}

// ---------------- weight transpose+convert: w[K][N] f32 -> wt[N][K] bf16 ----
__global__ void wconv_kernel(const float* __restrict__ w, bf16_t* __restrict__ wt,
                             int K, int N) {
  int idx = blockIdx.x * 256 + threadIdx.x;
  if (idx >= N * K) return;
  int n = idx / K, k = idx - n * K;
  wt[idx] = (bf16_t)w[(size_t)k * N + n];
}

// ---------------- LayerNorm (+optional shift/partition gather), f32 -> bf16 --
template <int MAP>
__global__ __launch_bounds__(256)
void ln_kernel(const float* __restrict__ xin, const float* __restrict__ g,
               const float* __restrict__ be, bf16_t* __restrict__ out) {
  int w = threadIdx.x >> 6, l = threadIdx.x & 63;
  int t = blockIdx.x * 4 + w;
  int s = MAP ? src_token(t) : t;
  const float* row = xin + (size_t)s * 384;
  float v[6], s1 = 0.f, s2 = 0.f;
#pragma unroll
  for (int i = 0; i < 6; i++) {
    v[i] = row[l + i * 64];
    s1 += v[i];
    s2 += v[i] * v[i];
  }
#pragma unroll
  for (int o = 32; o; o >>= 1) {
    s1 += __shfl_xor(s1, o);
    s2 += __shfl_xor(s2, o);
  }
  float mean = s1 * (1.f / 384.f);
  float var = s2 * (1.f / 384.f) - mean * mean;
  float rs = rsqrtf(var + 1e-5f);
  bf16_t* orow = out + (size_t)t * 384;
#pragma unroll
  for (int i = 0; i < 6; i++) {
    int idx = l + i * 64;
    orow[idx] = (bf16_t)((v[i] - mean) * rs * g[idx] + be[idx]);
  }
}

// ---------------- GEMM: C[M][N] = A[M][K]*Wt[N][K]^T + bias ------------------
// Round-9 proven geometry (BK=64, separate A/B tiles with 128B rows, both-
// sides XOR swizzle, XCD-chunked remap, VALU diet) + T4 counted-vmcnt double
// buffer: prologue stages 2 tiles (16 loads in flight/wave); each iteration
// waits vmcnt(8) (own tile landed, NEXT tile's 8 stay in flight — never drain
// to 0), raw s_barrier for cross-wave visibility, compute (compiler inserts
// lgkm waits; every ds_read consumed before barrier2 -> overwrite-safe),
// barrier, restage the freed buffer. Last iteration peeled with vmcnt(0).
// MODE 0: bf16 out. 1: bf16 gelu(out). 2: f32 scatter(src_token)+resid.
// MODE 3: f32 +resid (resid aliases outf; element owned by one thread).
template <int MODE>
__global__ __launch_bounds__(256, 2)
void gemm_bt(const bf16_t* __restrict__ A, const bf16_t* __restrict__ Wt,
             const float* __restrict__ bias, int K, int ldout, int ncols,
             bf16_t* outb, float* outf, const float* resid) {
  __shared__ __align__(16) bf16_t Alds[2][128 * 64];
  __shared__ __align__(16) bf16_t Blds[2][128 * 64];
  const int tid = threadIdx.x;
  const int l = tid & 63, w = tid >> 6;
  const int lr = l & 15, lq = l >> 4;
  // XCD-chunked bijective remap (nwg % 8 == 0)
  const int nwg = gridDim.x;
  const int orig = blockIdx.x;
  const int wgid = (orig & 7) * (nwg >> 3) + (orig >> 3);
  const int bn = wgid % ncols, bm = wgid / ncols;
  const int wr = w >> 1, wc = w & 1;

  // staging source (lane-dependent, swizzle-inverted): row&7 == l>>3 here,
  // so the inverse-swizzled source column is lane-only.
  const int srow = w * 8 + (l >> 3);
  const int scol = ((l & 7) ^ (l >> 3)) << 3;
  const bf16_t* ga = A + ((size_t)bm * 128 + srow) * K + scol;
  const bf16_t* gb = Wt + ((size_t)bn * 128 + srow) * K + scol;
  const size_t k32 = (size_t)32 * K;

  // K-invariant swizzled LDS read element-offsets
  int aoff[8], boff[8];
#pragma unroll
  for (int fi = 0; fi < 4; fi++) {
    int ra = wr * 64 + fi * 16 + lr;
    int rb = wc * 64 + fi * 16 + lr;
#pragma unroll
    for (int ks = 0; ks < 2; ks++) {
      aoff[fi * 2 + ks] = ra * 64 + ((ks * 32 + lq * 8) ^ ((ra & 7) << 3));
      boff[fi * 2 + ks] = rb * 64 + ((ks * 32 + lq * 8) ^ ((rb & 7) << 3));
    }
  }

  f32x4 acc[4][4] = {};

  auto stage = [&](int buf) {  // 8 gload_lds per wave per tile
#pragma unroll
    for (int r = 0; r < 4; r++) {
      gload_lds16(ga + r * k32, &Alds[buf][r * 2048 + w * 512]);
      gload_lds16(gb + r * k32, &Blds[buf][r * 2048 + w * 512]);
    }
    ga += 64;
    gb += 64;
  };
  auto compute = [&](int buf) {
#pragma unroll
    for (int ks = 0; ks < 2; ks++) {
      bf16x8 af[4], bfr[4];
#pragma unroll
      for (int fi = 0; fi < 4; fi++)
        af[fi] = *(const bf16x8*)&Alds[buf][aoff[fi * 2 + ks]];
#pragma unroll
      for (int fj = 0; fj < 4; fj++)
        bfr[fj] = *(const bf16x8*)&Blds[buf][boff[fj * 2 + ks]];
#pragma unroll
      for (int fi = 0; fi < 4; fi++)
#pragma unroll
        for (int fj = 0; fj < 4; fj++)
          acc[fi][fj] = mfma16(af[fi], bfr[fj], acc[fi][fj]);
    }
  };

  const int nt = K >> 6;  // 6 or 24
  stage(0);
  stage(1);
  for (int t = 0; t < nt - 1; t++) {
    // own tile-t loads done; tile-(t+1)'s 8 stay in flight (never drain to 0)
    asm volatile("s_waitcnt vmcnt(8)" ::: "memory");
    __builtin_amdgcn_sched_barrier(0);
    __builtin_amdgcn_s_barrier();   // all waves' tile-t portions visible
    compute(t & 1);
    __builtin_amdgcn_s_barrier();   // all waves done reading buf (lgkm drained
                                    // via MFMA data deps before this point)
    if (t + 2 < nt) stage(t & 1);   // refill freed buffer with tile t+2
  }
  asm volatile("s_waitcnt vmcnt(0)" ::: "memory");
  __builtin_amdgcn_sched_barrier(0);
  __builtin_amdgcn_s_barrier();
  compute((nt - 1) & 1);

  // ---- epilogue ----
  float bv[4];
#pragma unroll
  for (int fj = 0; fj < 4; fj++)
    bv[fj] = bias[bn * 128 + wc * 64 + fj * 16 + lr];
#pragma unroll
  for (int fi = 0; fi < 4; fi++) {
#pragma unroll
    for (int reg = 0; reg < 4; reg++) {
      int grow = bm * 128 + wr * 64 + fi * 16 + lq * 4 + reg;
      size_t rbase;
      if constexpr (MODE == 2)
        rbase = (size_t)src_token(grow) * ldout;
      else
        rbase = (size_t)grow * ldout;
#pragma unroll
      for (int fj = 0; fj < 4; fj++) {
        int gcol = bn * 128 + wc * 64 + fj * 16 + lr;
        float val = acc[fi][fj][reg] + bv[fj];
        if constexpr (MODE == 0) {
          outb[rbase + gcol] = (bf16_t)val;
        } else if constexpr (MODE == 1) {
          // tanh-form GELU: x * sigmoid(1.59577(x + 0.044715 x^3))
          float z = -1.5957691216f * val * fmaf(0.044715f, val * val, 1.0f);
          val = val / (1.0f + __expf(z));
          outb[rbase + gcol] = (bf16_t)val;
        } else {
          outf[rbase + gcol] = val + resid[rbase + gcol];
        }
      }
    }
  }
}

// ---------------- per-(window, head) attention (staged, swizzled) -----------
__global__ __launch_bounds__(64)
void attn_kernel(const bf16_t* __restrict__ qkv, const float* __restrict__ btab,
                 bf16_t* __restrict__ aout) {
  __shared__ __align__(16) bf16_t Qs[64 * 32];
  __shared__ __align__(16) bf16_t Ks[64 * 32];
  __shared__ __align__(16) bf16_t Vt[32 * 64];
  __shared__ __align__(16) bf16_t Ps[64 * 64];
  const int win = blockIdx.x, h = blockIdx.y;
  const int l = threadIdx.x, lr = l & 15, lq = l >> 4;

  {
    const bf16_t* qrow = qkv + ((size_t)win * 64 + l) * 1152 + h * 32;
#pragma unroll
    for (int c = 0; c < 4; c++) {
      *(bf16x8*)&Qs[l * 32 + c * 8] = *(const bf16x8*)&qrow[c * 8];
      *(bf16x8*)&Ks[l * 32 + c * 8] = *(const bf16x8*)&qrow[384 + c * 8];
    }
#pragma unroll
    for (int c = 0; c < 4; c++) {
      bf16x8 tv = *(const bf16x8*)&qrow[768 + c * 8];
#pragma unroll
      for (int e = 0; e < 8; e++) {
        int vr = c * 8 + e;
        Vt[vr * 64 + (l ^ ((vr & 7) << 3))] = tv[e];  // swizzled col
      }
    }
  }
  __syncthreads();

  // S = Q K^T  (64x64, K=32)
  f32x4 sacc[4][4] = {};
  {
    bf16x8 a[4], b[4];
#pragma unroll
    for (int fi = 0; fi < 4; fi++)
      a[fi] = *(const bf16x8*)&Qs[(fi * 16 + lr) * 32 + lq * 8];
#pragma unroll
    for (int fj = 0; fj < 4; fj++)
      b[fj] = *(const bf16x8*)&Ks[(fj * 16 + lr) * 32 + lq * 8];
#pragma unroll
    for (int fi = 0; fi < 4; fi++)
#pragma unroll
      for (int fj = 0; fj < 4; fj++)
        sacc[fi][fj] = mfma16(a[fi], b[fj], sacc[fi][fj]);
  }

  const int widx = win & 63;
  const int wh = widx >> 3, ww = widx & 7;
  const float scale = 0.17677669529663687f;  // 32^-0.5
#pragma unroll
  for (int fi = 0; fi < 4; fi++) {
#pragma unroll
    for (int reg = 0; reg < 4; reg++) {
      int row = fi * 16 + lq * 4 + reg;  // C/D: row=(l>>4)*4+reg (+fi*16)
      int i1 = row >> 3, j1 = row & 7;
      int ly1 = (wh == 7) ? (i1 >= 4 ? 2 : 1) : 0;
      int lx1 = (ww == 7) ? (j1 >= 4 ? 2 : 1) : 0;
      float vals[4], m = -1e30f;
#pragma unroll
      for (int fj = 0; fj < 4; fj++) {
        int col = fj * 16 + lr;  // C/D: col=l&15 (+fj*16)
        int i2 = col >> 3, j2 = col & 7;
        float v = sacc[fi][fj][reg] * scale +
                  btab[((i1 - i2 + 7) * 15 + (j1 - j2 + 7)) * 12 + h];
        int ly2 = (wh == 7) ? (i2 >= 4 ? 2 : 1) : 0;
        int lx2 = (ww == 7) ? (j2 >= 4 ? 2 : 1) : 0;
        if (ly1 != ly2 || lx1 != lx2) v -= 100.f;
        vals[fj] = v;
        m = fmaxf(m, v);
      }
#pragma unroll
      for (int o = 1; o < 16; o <<= 1) m = fmaxf(m, __shfl_xor(m, o));
      float ssum = 0.f;
#pragma unroll
      for (int fj = 0; fj < 4; fj++) {
        vals[fj] = __expf(vals[fj] - m);
        ssum += vals[fj];
      }
#pragma unroll
      for (int o = 1; o < 16; o <<= 1) ssum += __shfl_xor(ssum, o);
      float inv = 1.f / ssum;
      int sw = (row & 7) << 3;
#pragma unroll
      for (int fj = 0; fj < 4; fj++)
        Ps[row * 64 + ((fj * 16 + lr) ^ sw)] = (bf16_t)(vals[fj] * inv);
    }
  }
  __syncthreads();

  // O = P V  (64x32, K=64); swizzled Ps / Vt reads (conflict-free)
  f32x4 oacc[4][2] = {};
#pragma unroll
  for (int kc = 0; kc < 2; kc++) {
    bf16x8 pa[4], vb[2];
#pragma unroll
    for (int fi = 0; fi < 4; fi++) {
      int row = fi * 16 + lr;
      pa[fi] = *(const bf16x8*)&Ps[row * 64 + ((kc * 32 + lq * 8) ^ ((row & 7) << 3))];
    }
#pragma unroll
    for (int fj = 0; fj < 2; fj++) {
      int row = fj * 16 + lr;
      vb[fj] = *(const bf16x8*)&Vt[row * 64 + ((kc * 32 + lq * 8) ^ ((row & 7) << 3))];
    }
#pragma unroll
    for (int fi = 0; fi < 4; fi++)
#pragma unroll
      for (int fj = 0; fj < 2; fj++)
        oacc[fi][fj] = mfma16(pa[fi], vb[fj], oacc[fi][fj]);
  }
#pragma unroll
  for (int fi = 0; fi < 4; fi++)
#pragma unroll
    for (int reg = 0; reg < 4; reg++) {
      int row = fi * 16 + lq * 4 + reg;
      size_t rb = ((size_t)win * 64 + row) * 384 + h * 32;
#pragma unroll
      for (int fj = 0; fj < 2; fj++)
        aout[rb + fj * 16 + lr] = (bf16_t)oacc[fi][fj][reg];
    }
}

// ---------------------------------------------------------------------------
extern "C" void kernel_launch(void* const* d_in, const int* in_sizes, int n_in,
                              void* d_out, int out_size, void* d_ws, size_t ws_size,
                              hipStream_t stream) {
  (void)in_sizes; (void)n_in; (void)out_size; (void)ws_size;
  const float* x      = (const float*)d_in[0];
  const float* gamma1 = (const float*)d_in[1];
  const float* beta1  = (const float*)d_in[2];
  const float* w_qkv  = (const float*)d_in[3];
  const float* b_qkv  = (const float*)d_in[4];
  const float* btab   = (const float*)d_in[5];
  const float* w_proj = (const float*)d_in[6];
  const float* b_proj = (const float*)d_in[7];
  const float* gamma2 = (const float*)d_in[8];
  const float* beta2  = (const float*)d_in[9];
  const float* w_fc1  = (const float*)d_in[10];
  const float* b_fc1  = (const float*)d_in[11];
  const float* w_fc2  = (const float*)d_in[12];
  const float* b_fc2  = (const float*)d_in[13];
  float* out = (float*)d_out;

  char* ws = (char*)d_ws;
  size_t off = 0;
  auto alloc = [&](size_t bytes) {
    void* p = ws + off;
    off += (bytes + 255) & ~(size_t)255;
    return p;
  };
  bf16_t* wqkvT  = (bf16_t*)alloc((size_t)1152 * 384 * 2);
  bf16_t* wprojT = (bf16_t*)alloc((size_t)384 * 384 * 2);
  bf16_t* wfc1T  = (bf16_t*)alloc((size_t)1536 * 384 * 2);
  bf16_t* wfc2T  = (bf16_t*)alloc((size_t)384 * 1536 * 2);
  // qkv rows [TOK][1152] alias mlp hidden [TOK][1536]; lifetimes disjoint.
  char* big = (char*)alloc((size_t)TOK * 1536 * 2);
  bf16_t* bufA = (bf16_t*)big;  // qkv rows
  bf16_t* bufH = (bf16_t*)big;  // mlp hidden
  bf16_t* bufB = (bf16_t*)alloc((size_t)TOK * 384 * 2);  // ln1/attn/ln2 rows

  wconv_kernel<<<(1152 * 384 + 255) / 256, 256, 0, stream>>>(w_qkv, wqkvT, 384, 1152);
  wconv_kernel<<<(384 * 384 + 255) / 256, 256, 0, stream>>>(w_proj, wprojT, 384, 384);
  wconv_kernel<<<(384 * 1536 + 255) / 256, 256, 0, stream>>>(w_fc1, wfc1T, 384, 1536);
  wconv_kernel<<<(1536 * 384 + 255) / 256, 256, 0, stream>>>(w_fc2, wfc2T, 1536, 384);

  // LN1 + roll + window partition -> bufB [131072][384] bf16
  ln_kernel<1><<<TOK / 4, 256, 0, stream>>>(x, gamma1, beta1, bufB);
  // QKV: [131072,384] x [384,1152] -> bufA bf16   (grid 9*1024, %8==0)
  gemm_bt<0><<<9 * (TOK / 128), 256, 0, stream>>>(
      bufB, wqkvT, b_qkv, 384, 1152, 9, bufA, nullptr, nullptr);
  // windowed attention -> bufB [131072][384] bf16
  attn_kernel<<<dim3(NWIN, 12), 64, 0, stream>>>(bufA, btab, bufB);
  // proj + un-roll scatter + residual(x) -> out (x1, f32)  (grid 3*1024)
  gemm_bt<2><<<3 * (TOK / 128), 256, 0, stream>>>(
      bufB, wprojT, b_proj, 384, 384, 3, nullptr, out, x);
  // LN2 -> bufB bf16
  ln_kernel<0><<<TOK / 4, 256, 0, stream>>>(out, gamma2, beta2, bufB);
  // FC1 + fast GELU -> bufH [131072][1536] bf16  (grid 12*1024)
  gemm_bt<1><<<12 * (TOK / 128), 256, 0, stream>>>(
      bufB, wfc1T, b_fc1, 384, 1536, 12, bufH, nullptr, nullptr);
  // FC2 + residual(out, in-place) -> out  (grid 3*1024)
  gemm_bt<3><<<3 * (TOK / 128), 256, 0, stream>>>(
      bufH, wfc2T, b_fc2, 1536, 384, 3, nullptr, out, out);
}

// Round 12
// 1250.499 us; speedup vs baseline: 1.1558x; 1.1558x over previous
//
#include <hip/hip_runtime.h>
#include <hip/hip_bf16.h>

typedef __bf16 bf16_t;
typedef __bf16 bf16x8 __attribute__((ext_vector_type(8)));
typedef float f32x4 __attribute__((ext_vector_type(4)));

#define DI __device__ __forceinline__

static constexpr int TOK = 131072;  // 32 batches * 64*64 tokens
static constexpr int NWIN = 2048;   // 32 * 64 windows

// window-order token t -> source image token (LN1 gather) == proj scatter dest.
DI int src_token(int t) {
  int b = t >> 12;
  int widx = (t >> 6) & 63;
  int n = t & 63;
  int wh = widx >> 3, ww = widx & 7;
  int i = n >> 3, j = n & 7;
  int y = ((wh << 3) + i + 4) & 63;
  int x2 = ((ww << 3) + j + 4) & 63;
  return (b << 12) + (y << 6) + x2;
}

DI f32x4 mfma16(bf16x8 a, bf16x8 b, f32x4 c) {
  return __builtin_amdgcn_mfma_f32_16x16x32_bf16(a, b, c, 0, 0, 0);
}

DI void gload_lds16(const bf16_t* g, bf16_t* l) {
  __builtin_amdgcn_global_load_lds(
      (__attribute__((address_space(1))) void*)const_cast<bf16_t*>(g),
      (__attribute__((address_space(3))) void*)l, 16, 0, 0);
}

DI unsigned pack2(float a, float b) {
  union { bf16_t h[2]; unsigned u; } p;
  p.h[0] = (bf16_t)a;
  p.h[1] = (bf16_t)b;
  return p.u;
}

// ---------------- weight transpose+convert: w[K][N] f32 -> wt[N][K] bf16 ----
__global__ void wconv_kernel(const float* __restrict__ w, bf16_t* __restrict__ wt,
                             int K, int N) {
  int idx = blockIdx.x * 256 + threadIdx.x;
  if (idx >= N * K) return;
  int n = idx / K, k = idx - n * K;
  wt[idx] = (bf16_t)w[(size_t)k * N + n];
}

// ---------------- LayerNorm (+optional shift/partition gather), f32 -> bf16 --
// Vectorized (G13): lane owns 6 contiguous cols; 3x float2 loads (8B/lane)
// for x/gamma/beta, 3x packed-uint bf16 stores (vs 4B/2B scalar before).
template <int MAP>
__global__ __launch_bounds__(256)
void ln_kernel(const float* __restrict__ xin, const float* __restrict__ g,
               const float* __restrict__ be, bf16_t* __restrict__ out) {
  int w = threadIdx.x >> 6, l = threadIdx.x & 63;
  int t = blockIdx.x * 4 + w;
  int s = MAP ? src_token(t) : t;
  const float* row = xin + (size_t)s * 384 + l * 6;  // byte 24l: 8-aligned
  float2 v01 = *(const float2*)(row);
  float2 v23 = *(const float2*)(row + 2);
  float2 v45 = *(const float2*)(row + 4);
  float v[6] = {v01.x, v01.y, v23.x, v23.y, v45.x, v45.y};
  float s1 = 0.f, s2 = 0.f;
#pragma unroll
  for (int i = 0; i < 6; i++) {
    s1 += v[i];
    s2 += v[i] * v[i];
  }
#pragma unroll
  for (int o = 32; o; o >>= 1) {
    s1 += __shfl_xor(s1, o);
    s2 += __shfl_xor(s2, o);
  }
  float mean = s1 * (1.f / 384.f);
  float var = s2 * (1.f / 384.f) - mean * mean;
  float rs = rsqrtf(var + 1e-5f);
  const float* gp = g + l * 6;
  const float* bp = be + l * 6;
  float2 g01 = *(const float2*)(gp), g23 = *(const float2*)(gp + 2),
         g45 = *(const float2*)(gp + 4);
  float2 b01 = *(const float2*)(bp), b23 = *(const float2*)(bp + 2),
         b45 = *(const float2*)(bp + 4);
  float gg[6] = {g01.x, g01.y, g23.x, g23.y, g45.x, g45.y};
  float bb[6] = {b01.x, b01.y, b23.x, b23.y, b45.x, b45.y};
  float y[6];
#pragma unroll
  for (int i = 0; i < 6; i++) y[i] = (v[i] - mean) * rs * gg[i] + bb[i];
  unsigned* op = (unsigned*)(out + (size_t)t * 384 + l * 6);  // byte 12l: 4-aligned
  op[0] = pack2(y[0], y[1]);
  op[1] = pack2(y[2], y[3]);
  op[2] = pack2(y[4], y[5]);
}

// ---------------- GEMM: C[M][N] = A[M][K]*Wt[N][K]^T + bias ------------------
// Round-9 proven kernel VERBATIM (best measured structure): single-buffered
// 32KB LDS, BK=64, 2 barriers/K-tile, both-sides XOR swizzle, XCD-chunked
// remap, VALU diet (precomputed swizzled offsets, pointer-bump staging).
// Four pipeline variants (r3/r8/r10/r11) all lost to this at these shapes.
// MODE 0: bf16 out. 1: bf16 gelu(out). 2: f32 scatter(src_token)+resid.
// MODE 3: f32 +resid (resid aliases outf; element owned by one thread).
template <int MODE>
__global__ __launch_bounds__(256, 4)
void gemm_bt(const bf16_t* __restrict__ A, const bf16_t* __restrict__ Wt,
             const float* __restrict__ bias, int K, int ldout, int ncols,
             bf16_t* outb, float* outf, const float* resid) {
  __shared__ __align__(16) bf16_t Alds[128 * 64];
  __shared__ __align__(16) bf16_t Blds[128 * 64];
  const int tid = threadIdx.x;
  const int l = tid & 63, w = tid >> 6;
  const int lr = l & 15, lq = l >> 4;
  // XCD-chunked bijective remap (nwg % 8 == 0)
  const int nwg = gridDim.x;
  const int orig = blockIdx.x;
  const int wgid = (orig & 7) * (nwg >> 3) + (orig >> 3);
  const int bn = wgid % ncols, bm = wgid / ncols;
  const int wr = w >> 1, wc = w & 1;

  // staging source (lane-dependent, swizzle-inverted): row&7 == l>>3 here,
  // so the inverse-swizzled source column is lane-only.
  const int srow = w * 8 + (l >> 3);
  const int scol = ((l & 7) ^ (l >> 3)) << 3;
  const bf16_t* ga = A + ((size_t)bm * 128 + srow) * K + scol;
  const bf16_t* gb = Wt + ((size_t)bn * 128 + srow) * K + scol;
  const size_t k32 = (size_t)32 * K;
  bf16_t* la = &Alds[w * 512];  // wave-uniform LDS dest base
  bf16_t* lb = &Blds[w * 512];

  // K-invariant swizzled LDS read element-offsets
  int aoff[8], boff[8];
#pragma unroll
  for (int fi = 0; fi < 4; fi++) {
    int ra = wr * 64 + fi * 16 + lr;
    int rb = wc * 64 + fi * 16 + lr;
#pragma unroll
    for (int ks = 0; ks < 2; ks++) {
      aoff[fi * 2 + ks] = ra * 64 + ((ks * 32 + lq * 8) ^ ((ra & 7) << 3));
      boff[fi * 2 + ks] = rb * 64 + ((ks * 32 + lq * 8) ^ ((rb & 7) << 3));
    }
  }

  f32x4 acc[4][4] = {};
  const int nt = K >> 6;
  for (int t = 0; t < nt; t++) {
#pragma unroll
    for (int r = 0; r < 4; r++) {
      gload_lds16(ga + r * k32, la + r * 2048);
      gload_lds16(gb + r * k32, lb + r * 2048);
    }
    ga += 64;
    gb += 64;
    __syncthreads();
#pragma unroll
    for (int ks = 0; ks < 2; ks++) {
      bf16x8 af[4], bfr[4];
#pragma unroll
      for (int fi = 0; fi < 4; fi++)
        af[fi] = *(const bf16x8*)&Alds[aoff[fi * 2 + ks]];
#pragma unroll
      for (int fj = 0; fj < 4; fj++)
        bfr[fj] = *(const bf16x8*)&Blds[boff[fj * 2 + ks]];
#pragma unroll
      for (int fi = 0; fi < 4; fi++)
#pragma unroll
        for (int fj = 0; fj < 4; fj++)
          acc[fi][fj] = mfma16(af[fi], bfr[fj], acc[fi][fj]);
    }
    __syncthreads();
  }

  // ---- epilogue ----
  float bv[4];
#pragma unroll
  for (int fj = 0; fj < 4; fj++)
    bv[fj] = bias[bn * 128 + wc * 64 + fj * 16 + lr];
#pragma unroll
  for (int fi = 0; fi < 4; fi++) {
#pragma unroll
    for (int reg = 0; reg < 4; reg++) {
      int grow = bm * 128 + wr * 64 + fi * 16 + lq * 4 + reg;
      size_t rbase;
      if constexpr (MODE == 2)
        rbase = (size_t)src_token(grow) * ldout;
      else
        rbase = (size_t)grow * ldout;
#pragma unroll
      for (int fj = 0; fj < 4; fj++) {
        int gcol = bn * 128 + wc * 64 + fj * 16 + lr;
        float val = acc[fi][fj][reg] + bv[fj];
        if constexpr (MODE == 0) {
          outb[rbase + gcol] = (bf16_t)val;
        } else if constexpr (MODE == 1) {
          // tanh-form GELU: x * sigmoid(1.59577(x + 0.044715 x^3))
          float z = -1.5957691216f * val * fmaf(0.044715f, val * val, 1.0f);
          val = val / (1.0f + __expf(z));
          outb[rbase + gcol] = (bf16_t)val;
        } else {
          outf[rbase + gcol] = val + resid[rbase + gcol];
        }
      }
    }
  }
}

// ---------------- per-(window, head) attention ------------------------------
// Q/K fragments load DIRECTLY from global (each frag element is a contiguous
// 16B chunk at the same cache lines the old staging touched) — removes the
// Qs/Ks LDS round trip. Only V (transpose) and P stay in LDS: 12KB/block.
__global__ __launch_bounds__(64)
void attn_kernel(const bf16_t* __restrict__ qkv, const float* __restrict__ btab,
                 bf16_t* __restrict__ aout) {
  __shared__ __align__(16) bf16_t Vt[32 * 64];
  __shared__ __align__(16) bf16_t Ps[64 * 64];
  const int win = blockIdx.x, h = blockIdx.y;
  const int l = threadIdx.x, lr = l & 15, lq = l >> 4;
  const bf16_t* qbase = qkv + (size_t)win * 64 * 1152 + h * 32;

  // stage V transposed (swizzled cols)
  {
    const bf16_t* vrow = qbase + l * 1152 + 768;
#pragma unroll
    for (int c = 0; c < 4; c++) {
      bf16x8 tv = *(const bf16x8*)&vrow[c * 8];
#pragma unroll
      for (int e = 0; e < 8; e++) {
        int vr = c * 8 + e;
        Vt[vr * 64 + (l ^ ((vr & 7) << 3))] = tv[e];
      }
    }
  }

  // S = Q K^T  (64x64, K=32) — direct global fragment loads
  f32x4 sacc[4][4] = {};
  {
    bf16x8 a[4], b[4];
#pragma unroll
    for (int fi = 0; fi < 4; fi++)
      a[fi] = *(const bf16x8*)(qbase + (size_t)(fi * 16 + lr) * 1152 + lq * 8);
#pragma unroll
    for (int fj = 0; fj < 4; fj++)
      b[fj] = *(const bf16x8*)(qbase + 384 + (size_t)(fj * 16 + lr) * 1152 + lq * 8);
#pragma unroll
    for (int fi = 0; fi < 4; fi++)
#pragma unroll
      for (int fj = 0; fj < 4; fj++)
        sacc[fi][fj] = mfma16(a[fi], b[fj], sacc[fi][fj]);
  }

  const int widx = win & 63;
  const int wh = widx >> 3, ww = widx & 7;
  const float scale = 0.17677669529663687f;  // 32^-0.5
#pragma unroll
  for (int fi = 0; fi < 4; fi++) {
#pragma unroll
    for (int reg = 0; reg < 4; reg++) {
      int row = fi * 16 + lq * 4 + reg;  // C/D: row=(l>>4)*4+reg (+fi*16)
      int i1 = row >> 3, j1 = row & 7;
      int ly1 = (wh == 7) ? (i1 >= 4 ? 2 : 1) : 0;
      int lx1 = (ww == 7) ? (j1 >= 4 ? 2 : 1) : 0;
      float vals[4], m = -1e30f;
#pragma unroll
      for (int fj = 0; fj < 4; fj++) {
        int col = fj * 16 + lr;  // C/D: col=l&15 (+fj*16)
        int i2 = col >> 3, j2 = col & 7;
        float v = sacc[fi][fj][reg] * scale +
                  btab[((i1 - i2 + 7) * 15 + (j1 - j2 + 7)) * 12 + h];
        int ly2 = (wh == 7) ? (i2 >= 4 ? 2 : 1) : 0;
        int lx2 = (ww == 7) ? (j2 >= 4 ? 2 : 1) : 0;
        if (ly1 != ly2 || lx1 != lx2) v -= 100.f;
        vals[fj] = v;
        m = fmaxf(m, v);
      }
#pragma unroll
      for (int o = 1; o < 16; o <<= 1) m = fmaxf(m, __shfl_xor(m, o));
      float ssum = 0.f;
#pragma unroll
      for (int fj = 0; fj < 4; fj++) {
        vals[fj] = __expf(vals[fj] - m);
        ssum += vals[fj];
      }
#pragma unroll
      for (int o = 1; o < 16; o <<= 1) ssum += __shfl_xor(ssum, o);
      float inv = 1.f / ssum;
      int sw = (row & 7) << 3;
#pragma unroll
      for (int fj = 0; fj < 4; fj++)
        Ps[row * 64 + ((fj * 16 + lr) ^ sw)] = (bf16_t)(vals[fj] * inv);
    }
  }
  __syncthreads();

  // O = P V  (64x32, K=64); swizzled Ps / Vt reads (conflict-free)
  f32x4 oacc[4][2] = {};
#pragma unroll
  for (int kc = 0; kc < 2; kc++) {
    bf16x8 pa[4], vb[2];
#pragma unroll
    for (int fi = 0; fi < 4; fi++) {
      int row = fi * 16 + lr;
      pa[fi] = *(const bf16x8*)&Ps[row * 64 + ((kc * 32 + lq * 8) ^ ((row & 7) << 3))];
    }
#pragma unroll
    for (int fj = 0; fj < 2; fj++) {
      int row = fj * 16 + lr;
      vb[fj] = *(const bf16x8*)&Vt[row * 64 + ((kc * 32 + lq * 8) ^ ((row & 7) << 3))];
    }
#pragma unroll
    for (int fi = 0; fi < 4; fi++)
#pragma unroll
      for (int fj = 0; fj < 2; fj++)
        oacc[fi][fj] = mfma16(pa[fi], vb[fj], oacc[fi][fj]);
  }
#pragma unroll
  for (int fi = 0; fi < 4; fi++)
#pragma unroll
    for (int reg = 0; reg < 4; reg++) {
      int row = fi * 16 + lq * 4 + reg;
      size_t rb = ((size_t)win * 64 + row) * 384 + h * 32;
#pragma unroll
      for (int fj = 0; fj < 2; fj++)
        aout[rb + fj * 16 + lr] = (bf16_t)oacc[fi][fj][reg];
    }
}

// ---------------------------------------------------------------------------
extern "C" void kernel_launch(void* const* d_in, const int* in_sizes, int n_in,
                              void* d_out, int out_size, void* d_ws, size_t ws_size,
                              hipStream_t stream) {
  (void)in_sizes; (void)n_in; (void)out_size; (void)ws_size;
  const float* x      = (const float*)d_in[0];
  const float* gamma1 = (const float*)d_in[1];
  const float* beta1  = (const float*)d_in[2];
  const float* w_qkv  = (const float*)d_in[3];
  const float* b_qkv  = (const float*)d_in[4];
  const float* btab   = (const float*)d_in[5];
  const float* w_proj = (const float*)d_in[6];
  const float* b_proj = (const float*)d_in[7];
  const float* gamma2 = (const float*)d_in[8];
  const float* beta2  = (const float*)d_in[9];
  const float* w_fc1  = (const float*)d_in[10];
  const float* b_fc1  = (const float*)d_in[11];
  const float* w_fc2  = (const float*)d_in[12];
  const float* b_fc2  = (const float*)d_in[13];
  float* out = (float*)d_out;

  char* ws = (char*)d_ws;
  size_t off = 0;
  auto alloc = [&](size_t bytes) {
    void* p = ws + off;
    off += (bytes + 255) & ~(size_t)255;
    return p;
  };
  bf16_t* wqkvT  = (bf16_t*)alloc((size_t)1152 * 384 * 2);
  bf16_t* wprojT = (bf16_t*)alloc((size_t)384 * 384 * 2);
  bf16_t* wfc1T  = (bf16_t*)alloc((size_t)1536 * 384 * 2);
  bf16_t* wfc2T  = (bf16_t*)alloc((size_t)384 * 1536 * 2);
  // qkv rows [TOK][1152] alias mlp hidden [TOK][1536]; lifetimes disjoint.
  char* big = (char*)alloc((size_t)TOK * 1536 * 2);
  bf16_t* bufA = (bf16_t*)big;  // qkv rows
  bf16_t* bufH = (bf16_t*)big;  // mlp hidden
  bf16_t* bufB = (bf16_t*)alloc((size_t)TOK * 384 * 2);  // ln1/attn/ln2 rows

  wconv_kernel<<<(1152 * 384 + 255) / 256, 256, 0, stream>>>(w_qkv, wqkvT, 384, 1152);
  wconv_kernel<<<(384 * 384 + 255) / 256, 256, 0, stream>>>(w_proj, wprojT, 384, 384);
  wconv_kernel<<<(384 * 1536 + 255) / 256, 256, 0, stream>>>(w_fc1, wfc1T, 384, 1536);
  wconv_kernel<<<(1536 * 384 + 255) / 256, 256, 0, stream>>>(w_fc2, wfc2T, 1536, 384);

  // LN1 + roll + window partition -> bufB [131072][384] bf16
  ln_kernel<1><<<TOK / 4, 256, 0, stream>>>(x, gamma1, beta1, bufB);
  // QKV: [131072,384] x [384,1152] -> bufA bf16   (grid 9*1024, %8==0)
  gemm_bt<0><<<9 * (TOK / 128), 256, 0, stream>>>(
      bufB, wqkvT, b_qkv, 384, 1152, 9, bufA, nullptr, nullptr);
  // windowed attention -> bufB [131072][384] bf16
  attn_kernel<<<dim3(NWIN, 12), 64, 0, stream>>>(bufA, btab, bufB);
  // proj + un-roll scatter + residual(x) -> out (x1, f32)  (grid 3*1024)
  gemm_bt<2><<<3 * (TOK / 128), 256, 0, stream>>>(
      bufB, wprojT, b_proj, 384, 384, 3, nullptr, out, x);
  // LN2 -> bufB bf16
  ln_kernel<0><<<TOK / 4, 256, 0, stream>>>(out, gamma2, beta2, bufB);
  // FC1 + fast GELU -> bufH [131072][1536] bf16  (grid 12*1024)
  gemm_bt<1><<<12 * (TOK / 128), 256, 0, stream>>>(
      bufB, wfc1T, b_fc1, 384, 1536, 12, bufH, nullptr, nullptr);
  // FC2 + residual(out, in-place) -> out  (grid 3*1024)
  gemm_bt<3><<<3 * (TOK / 128), 256, 0, stream>>>(
      bufH, wfc2T, b_fc2, 1536, 384, 3, nullptr, out, out);
}

// Round 13
// 1184.525 us; speedup vs baseline: 1.2202x; 1.0557x over previous
//
#include <hip/hip_runtime.h>
#include <hip/hip_bf16.h>

typedef __bf16 bf16_t;
typedef __bf16 bf16x8 __attribute__((ext_vector_type(8)));
typedef float f32x4 __attribute__((ext_vector_type(4)));

#define DI __device__ __forceinline__

static constexpr int TOK = 131072;  // 32 batches * 64*64 tokens
static constexpr int NWIN = 2048;   // 32 * 64 windows

// window-order token t -> source image token (LN1 gather) == proj scatter dest.
DI int src_token(int t) {
  int b = t >> 12;
  int widx = (t >> 6) & 63;
  int n = t & 63;
  int wh = widx >> 3, ww = widx & 7;
  int i = n >> 3, j = n & 7;
  int y = ((wh << 3) + i + 4) & 63;
  int x2 = ((ww << 3) + j + 4) & 63;
  return (b << 12) + (y << 6) + x2;
}

DI f32x4 mfma16(bf16x8 a, bf16x8 b, f32x4 c) {
  return __builtin_amdgcn_mfma_f32_16x16x32_bf16(a, b, c, 0, 0, 0);
}

DI void gload_lds16(const bf16_t* g, bf16_t* l) {
  __builtin_amdgcn_global_load_lds(
      (__attribute__((address_space(1))) void*)const_cast<bf16_t*>(g),
      (__attribute__((address_space(3))) void*)l, 16, 0, 0);
}

// ------ merged weight transpose+convert (+Q-scale fold, +scaled b_qkv) ------
// w[K][N] f32 -> wt[N][K] bf16 for all four weights in ONE launch.
// Q-columns (n<384) of w_qkv and b_qkv absorb the HD^-0.5 softmax scale.
__global__ void wconv_all(const float* __restrict__ wq, const float* __restrict__ wp,
                          const float* __restrict__ w1, const float* __restrict__ w2,
                          const float* __restrict__ bq,
                          bf16_t* oq, bf16_t* op_, bf16_t* o1, bf16_t* o2,
                          float* bqs) {
  int idx = blockIdx.x * 256 + threadIdx.x;
  const float s = 0.17677669529663687f;  // 32^-0.5
  if (idx < 442368) {
    int n = idx / 384, k = idx - n * 384;
    float v = wq[(size_t)k * 1152 + n];
    if (n < 384) v *= s;
    oq[idx] = (bf16_t)v;
  } else if ((idx -= 442368) < 147456) {
    int n = idx / 384, k = idx - n * 384;
    op_[idx] = (bf16_t)wp[(size_t)k * 384 + n];
  } else if ((idx -= 147456) < 589824) {
    int n = idx / 384, k = idx - n * 384;
    o1[idx] = (bf16_t)w1[(size_t)k * 1536 + n];
  } else if ((idx -= 589824) < 589824) {
    int n = idx / 1536, k = idx - n * 1536;
    o2[idx] = (bf16_t)w2[(size_t)k * 384 + n];
  } else if ((idx -= 589824) < 1152) {
    bqs[idx] = bq[idx] * (idx < 384 ? s : 1.f);
  }
}

// ------ bias_full[4 classes][12 heads][64][64] = rel_bias + shift-mask ------
// Collapses the softmax's 64 per-thread btab gathers + mask-compare chain
// into one coalesced f32 load per 4 elements. cls = (wh==7)<<1 | (ww==7).
__global__ void bias_build(const float* __restrict__ btab, float* __restrict__ bf) {
  int idx = blockIdx.x * 256 + threadIdx.x;  // < 4*12*4096
  int c = idx & 63, r = (idx >> 6) & 63;
  int hh = idx >> 12;
  int h = hh % 12, cls = hh / 12;
  int i1 = r >> 3, j1 = r & 7, i2 = c >> 3, j2 = c & 7;
  float v = btab[((i1 - i2 + 7) * 15 + (j1 - j2 + 7)) * 12 + h];
  int wh7 = cls >> 1, ww7 = cls & 1;
  int ly1 = wh7 ? (i1 >= 4 ? 2 : 1) : 0;
  int ly2 = wh7 ? (i2 >= 4 ? 2 : 1) : 0;
  int lx1 = ww7 ? (j1 >= 4 ? 2 : 1) : 0;
  int lx2 = ww7 ? (j2 >= 4 ? 2 : 1) : 0;
  if (ly1 != ly2 || lx1 != lx2) v -= 100.f;
  bf[idx] = v;
}

// ---------------- LayerNorm (+optional shift/partition gather), f32 -> bf16 --
// r9-proven form: scalar l+i*64 accesses are fully coalesced (256B/instr).
template <int MAP>
__global__ __launch_bounds__(256)
void ln_kernel(const float* __restrict__ xin, const float* __restrict__ g,
               const float* __restrict__ be, bf16_t* __restrict__ out) {
  int w = threadIdx.x >> 6, l = threadIdx.x & 63;
  int t = blockIdx.x * 4 + w;
  int s = MAP ? src_token(t) : t;
  const float* row = xin + (size_t)s * 384;
  float v[6], s1 = 0.f, s2 = 0.f;
#pragma unroll
  for (int i = 0; i < 6; i++) {
    v[i] = row[l + i * 64];
    s1 += v[i];
    s2 += v[i] * v[i];
  }
#pragma unroll
  for (int o = 32; o; o >>= 1) {
    s1 += __shfl_xor(s1, o);
    s2 += __shfl_xor(s2, o);
  }
  float mean = s1 * (1.f / 384.f);
  float var = s2 * (1.f / 384.f) - mean * mean;
  float rs = rsqrtf(var + 1e-5f);
  bf16_t* orow = out + (size_t)t * 384;
#pragma unroll
  for (int i = 0; i < 6; i++) {
    int idx = l + i * 64;
    orow[idx] = (bf16_t)((v[i] - mean) * rs * g[idx] + be[idx]);
  }
}

// ---------------- GEMM: C[M][N] = A[M][K]*Wt[N][K]^T + bias ------------------
// Round-9 proven kernel (best measured): single-buffered 32KB LDS, BK=64,
// 2 barriers/K-tile, both-sides XOR swizzle, XCD-chunked remap, VALU diet.
// MODE 0: bf16 out. 1: bf16 gelu(out). 2: f32 scatter(src_token)+resid.
// MODE 3: f32 +resid (resid aliases outf; element owned by one thread).
template <int MODE>
__global__ __launch_bounds__(256, 4)
void gemm_bt(const bf16_t* __restrict__ A, const bf16_t* __restrict__ Wt,
             const float* __restrict__ bias, int K, int ldout, int ncols,
             bf16_t* outb, float* outf, const float* resid) {
  __shared__ __align__(16) bf16_t Alds[128 * 64];
  __shared__ __align__(16) bf16_t Blds[128 * 64];
  const int tid = threadIdx.x;
  const int l = tid & 63, w = tid >> 6;
  const int lr = l & 15, lq = l >> 4;
  const int nwg = gridDim.x;
  const int orig = blockIdx.x;
  const int wgid = (orig & 7) * (nwg >> 3) + (orig >> 3);
  const int bn = wgid % ncols, bm = wgid / ncols;
  const int wr = w >> 1, wc = w & 1;

  const int srow = w * 8 + (l >> 3);
  const int scol = ((l & 7) ^ (l >> 3)) << 3;
  const bf16_t* ga = A + ((size_t)bm * 128 + srow) * K + scol;
  const bf16_t* gb = Wt + ((size_t)bn * 128 + srow) * K + scol;
  const size_t k32 = (size_t)32 * K;
  bf16_t* la = &Alds[w * 512];
  bf16_t* lb = &Blds[w * 512];

  int aoff[8], boff[8];
#pragma unroll
  for (int fi = 0; fi < 4; fi++) {
    int ra = wr * 64 + fi * 16 + lr;
    int rb = wc * 64 + fi * 16 + lr;
#pragma unroll
    for (int ks = 0; ks < 2; ks++) {
      aoff[fi * 2 + ks] = ra * 64 + ((ks * 32 + lq * 8) ^ ((ra & 7) << 3));
      boff[fi * 2 + ks] = rb * 64 + ((ks * 32 + lq * 8) ^ ((rb & 7) << 3));
    }
  }

  f32x4 acc[4][4] = {};
  const int nt = K >> 6;
  for (int t = 0; t < nt; t++) {
#pragma unroll
    for (int r = 0; r < 4; r++) {
      gload_lds16(ga + r * k32, la + r * 2048);
      gload_lds16(gb + r * k32, lb + r * 2048);
    }
    ga += 64;
    gb += 64;
    __syncthreads();
#pragma unroll
    for (int ks = 0; ks < 2; ks++) {
      bf16x8 af[4], bfr[4];
#pragma unroll
      for (int fi = 0; fi < 4; fi++)
        af[fi] = *(const bf16x8*)&Alds[aoff[fi * 2 + ks]];
#pragma unroll
      for (int fj = 0; fj < 4; fj++)
        bfr[fj] = *(const bf16x8*)&Blds[boff[fj * 2 + ks]];
#pragma unroll
      for (int fi = 0; fi < 4; fi++)
#pragma unroll
        for (int fj = 0; fj < 4; fj++)
          acc[fi][fj] = mfma16(af[fi], bfr[fj], acc[fi][fj]);
    }
    __syncthreads();
  }

  float bv[4];
#pragma unroll
  for (int fj = 0; fj < 4; fj++)
    bv[fj] = bias[bn * 128 + wc * 64 + fj * 16 + lr];
#pragma unroll
  for (int fi = 0; fi < 4; fi++) {
#pragma unroll
    for (int reg = 0; reg < 4; reg++) {
      int grow = bm * 128 + wr * 64 + fi * 16 + lq * 4 + reg;
      size_t rbase;
      if constexpr (MODE == 2)
        rbase = (size_t)src_token(grow) * ldout;
      else
        rbase = (size_t)grow * ldout;
#pragma unroll
      for (int fj = 0; fj < 4; fj++) {
        int gcol = bn * 128 + wc * 64 + fj * 16 + lr;
        float val = acc[fi][fj][reg] + bv[fj];
        if constexpr (MODE == 0) {
          outb[rbase + gcol] = (bf16_t)val;
        } else if constexpr (MODE == 1) {
          // tanh-form GELU via fast sigmoid (rcp instead of div)
          float z = -1.5957691216f * val * fmaf(0.044715f, val * val, 1.0f);
          val = val * __builtin_amdgcn_rcpf(1.0f + __expf(z));
          outb[rbase + gcol] = (bf16_t)val;
        } else {
          outf[rbase + gcol] = val + resid[rbase + gcol];
        }
      }
    }
  }
}

// ---------------- per-(window, head) attention (r9 staging + bias table) ----
__global__ __launch_bounds__(64)
void attn_kernel(const bf16_t* __restrict__ qkv, const float* __restrict__ biasF,
                 bf16_t* __restrict__ aout) {
  __shared__ __align__(16) bf16_t Qs[64 * 32];
  __shared__ __align__(16) bf16_t Ks[64 * 32];
  __shared__ __align__(16) bf16_t Vt[32 * 64];
  __shared__ __align__(16) bf16_t Ps[64 * 64];
  const int win = blockIdx.x, h = blockIdx.y;
  const int l = threadIdx.x, lr = l & 15, lq = l >> 4;

  {
    const bf16_t* qrow = qkv + ((size_t)win * 64 + l) * 1152 + h * 32;
#pragma unroll
    for (int c = 0; c < 4; c++) {
      *(bf16x8*)&Qs[l * 32 + c * 8] = *(const bf16x8*)&qrow[c * 8];
      *(bf16x8*)&Ks[l * 32 + c * 8] = *(const bf16x8*)&qrow[384 + c * 8];
    }
#pragma unroll
    for (int c = 0; c < 4; c++) {
      bf16x8 tv = *(const bf16x8*)&qrow[768 + c * 8];
#pragma unroll
      for (int e = 0; e < 8; e++) {
        int vr = c * 8 + e;
        Vt[vr * 64 + (l ^ ((vr & 7) << 3))] = tv[e];  // swizzled col
      }
    }
  }
  __syncthreads();

  // S = Q K^T  (64x64, K=32); Q pre-scaled via weight fold
  f32x4 sacc[4][4] = {};
  {
    bf16x8 a[4], b[4];
#pragma unroll
    for (int fi = 0; fi < 4; fi++)
      a[fi] = *(const bf16x8*)&Qs[(fi * 16 + lr) * 32 + lq * 8];
#pragma unroll
    for (int fj = 0; fj < 4; fj++)
      b[fj] = *(const bf16x8*)&Ks[(fj * 16 + lr) * 32 + lq * 8];
#pragma unroll
    for (int fi = 0; fi < 4; fi++)
#pragma unroll
      for (int fj = 0; fj < 4; fj++)
        sacc[fi][fj] = mfma16(a[fi], b[fj], sacc[fi][fj]);
  }

  // softmax with precomputed bias+mask table (coalesced 64B row-segment loads)
  const int widx = win & 63;
  const int cls = (((widx >> 3) == 7) << 1) | ((widx & 7) == 7);
  const float* bfp = biasF + (((size_t)cls * 12 + h) << 12);
#pragma unroll
  for (int fi = 0; fi < 4; fi++) {
#pragma unroll
    for (int reg = 0; reg < 4; reg++) {
      int row = fi * 16 + lq * 4 + reg;  // C/D: row=(l>>4)*4+reg (+fi*16)
      const float* brow = bfp + row * 64 + lr;
      float vals[4], m = -1e30f;
#pragma unroll
      for (int fj = 0; fj < 4; fj++) {
        float v = sacc[fi][fj][reg] + brow[fj * 16];
        vals[fj] = v;
        m = fmaxf(m, v);
      }
#pragma unroll
      for (int o = 1; o < 16; o <<= 1) m = fmaxf(m, __shfl_xor(m, o));
      float ssum = 0.f;
#pragma unroll
      for (int fj = 0; fj < 4; fj++) {
        vals[fj] = __expf(vals[fj] - m);
        ssum += vals[fj];
      }
#pragma unroll
      for (int o = 1; o < 16; o <<= 1) ssum += __shfl_xor(ssum, o);
      float inv = 1.f / ssum;
      int sw = (row & 7) << 3;
#pragma unroll
      for (int fj = 0; fj < 4; fj++)
        Ps[row * 64 + ((fj * 16 + lr) ^ sw)] = (bf16_t)(vals[fj] * inv);
    }
  }
  __syncthreads();

  // O = P V  (64x32, K=64); swizzled Ps / Vt reads (conflict-free)
  f32x4 oacc[4][2] = {};
#pragma unroll
  for (int kc = 0; kc < 2; kc++) {
    bf16x8 pa[4], vb[2];
#pragma unroll
    for (int fi = 0; fi < 4; fi++) {
      int row = fi * 16 + lr;
      pa[fi] = *(const bf16x8*)&Ps[row * 64 + ((kc * 32 + lq * 8) ^ ((row & 7) << 3))];
    }
#pragma unroll
    for (int fj = 0; fj < 2; fj++) {
      int row = fj * 16 + lr;
      vb[fj] = *(const bf16x8*)&Vt[row * 64 + ((kc * 32 + lq * 8) ^ ((row & 7) << 3))];
    }
#pragma unroll
    for (int fi = 0; fi < 4; fi++)
#pragma unroll
      for (int fj = 0; fj < 2; fj++)
        oacc[fi][fj] = mfma16(pa[fi], vb[fj], oacc[fi][fj]);
  }
#pragma unroll
  for (int fi = 0; fi < 4; fi++)
#pragma unroll
    for (int reg = 0; reg < 4; reg++) {
      int row = fi * 16 + lq * 4 + reg;
      size_t rb = ((size_t)win * 64 + row) * 384 + h * 32;
#pragma unroll
      for (int fj = 0; fj < 2; fj++)
        aout[rb + fj * 16 + lr] = (bf16_t)oacc[fi][fj][reg];
    }
}

// ---------------------------------------------------------------------------
extern "C" void kernel_launch(void* const* d_in, const int* in_sizes, int n_in,
                              void* d_out, int out_size, void* d_ws, size_t ws_size,
                              hipStream_t stream) {
  (void)in_sizes; (void)n_in; (void)out_size; (void)ws_size;
  const float* x      = (const float*)d_in[0];
  const float* gamma1 = (const float*)d_in[1];
  const float* beta1  = (const float*)d_in[2];
  const float* w_qkv  = (const float*)d_in[3];
  const float* b_qkv  = (const float*)d_in[4];
  const float* btab   = (const float*)d_in[5];
  const float* w_proj = (const float*)d_in[6];
  const float* b_proj = (const float*)d_in[7];
  const float* gamma2 = (const float*)d_in[8];
  const float* beta2  = (const float*)d_in[9];
  const float* w_fc1  = (const float*)d_in[10];
  const float* b_fc1  = (const float*)d_in[11];
  const float* w_fc2  = (const float*)d_in[12];
  const float* b_fc2  = (const float*)d_in[13];
  float* out = (float*)d_out;

  char* ws = (char*)d_ws;
  size_t off = 0;
  auto alloc = [&](size_t bytes) {
    void* p = ws + off;
    off += (bytes + 255) & ~(size_t)255;
    return p;
  };
  bf16_t* wqkvT  = (bf16_t*)alloc((size_t)1152 * 384 * 2);
  bf16_t* wprojT = (bf16_t*)alloc((size_t)384 * 384 * 2);
  bf16_t* wfc1T  = (bf16_t*)alloc((size_t)1536 * 384 * 2);
  bf16_t* wfc2T  = (bf16_t*)alloc((size_t)384 * 1536 * 2);
  float*  bqs    = (float*)alloc((size_t)1152 * 4);
  float*  biasF  = (float*)alloc((size_t)4 * 12 * 4096 * 4);
  // qkv rows [TOK][1152] alias mlp hidden [TOK][1536]; lifetimes disjoint.
  char* big = (char*)alloc((size_t)TOK * 1536 * 2);
  bf16_t* bufA = (bf16_t*)big;  // qkv rows
  bf16_t* bufH = (bf16_t*)big;  // mlp hidden
  bf16_t* bufB = (bf16_t*)alloc((size_t)TOK * 384 * 2);  // ln1/attn/ln2 rows

  // merged weight conversion (+Q-scale fold) and bias table build
  wconv_all<<<(1769472 + 1152 + 255) / 256, 256, 0, stream>>>(
      w_qkv, w_proj, w_fc1, w_fc2, b_qkv, wqkvT, wprojT, wfc1T, wfc2T, bqs);
  bias_build<<<(4 * 12 * 4096) / 256, 256, 0, stream>>>(btab, biasF);

  // LN1 + roll + window partition -> bufB [131072][384] bf16
  ln_kernel<1><<<TOK / 4, 256, 0, stream>>>(x, gamma1, beta1, bufB);
  // QKV: [131072,384] x [384,1152] -> bufA bf16   (grid 9*1024, %8==0)
  gemm_bt<0><<<9 * (TOK / 128), 256, 0, stream>>>(
      bufB, wqkvT, bqs, 384, 1152, 9, bufA, nullptr, nullptr);
  // windowed attention -> bufB [131072][384] bf16
  attn_kernel<<<dim3(NWIN, 12), 64, 0, stream>>>(bufA, biasF, bufB);
  // proj + un-roll scatter + residual(x) -> out (x1, f32)  (grid 3*1024)
  gemm_bt<2><<<3 * (TOK / 128), 256, 0, stream>>>(
      bufB, wprojT, b_proj, 384, 384, 3, nullptr, out, x);
  // LN2 -> bufB bf16
  ln_kernel<0><<<TOK / 4, 256, 0, stream>>>(out, gamma2, beta2, bufB);
  // FC1 + fast GELU -> bufH [131072][1536] bf16  (grid 12*1024)
  gemm_bt<1><<<12 * (TOK / 128), 256, 0, stream>>>(
      bufB, wfc1T, b_fc1, 384, 1536, 12, bufH, nullptr, nullptr);
  // FC2 + residual(out, in-place) -> out  (grid 3*1024)
  gemm_bt<3><<<3 * (TOK / 128), 256, 0, stream>>>(
      bufH, wfc2T, b_fc2, 1536, 384, 3, nullptr, out, out);
}